// Round 11
// baseline (100.752 us; speedup 1.0000x reference)
//
#include <hip/hip_runtime.h>
#include <math.h>

#define B 8
#define C 3
#define H 1024
#define W 1024
#define L 1024
#define D 512
#define DH 128
#define NPIX (H * W)
#define NOISY_ELEMS (B * C * NPIX) // 25165824
#define TH 16                      // rows per strip in mega kernel

typedef float vf2 __attribute__((ext_vector_type(2)));
typedef float vf4 __attribute__((ext_vector_type(4)));

struct BlurW { float w[21]; };

// ---------------- kernel A: colsum + (winner block) MLP head ----------------
// 256 blocks x 128 threads. Block (b, chunk) sums 32 rows of batch b into
// partial[(b*32+chunk)*512 + 4t]. Last block per batch (device-scope counter)
// runs the head MLP for that batch inline.
__global__ __launch_bounds__(128) void colsum_head_kernel(
        const float* __restrict__ feat, float* __restrict__ partial,
        int* __restrict__ counters,
        const float* __restrict__ W1, const float* __restrict__ b1,
        const float* __restrict__ ln_g, const float* __restrict__ ln_b,
        const float* __restrict__ W2, const float* __restrict__ b2,
        float* __restrict__ ab, float* __restrict__ out_tail) {
    int blk = blockIdx.x;            // 0..255
    int b = blk >> 5, chunk = blk & 31;
    int j = threadIdx.x;             // 0..127
    int d4 = 4 * j;

    const float* base = feat + (size_t)b * (L * D) + (size_t)chunk * 32 * D + d4;
    vf4 s = {0.f, 0.f, 0.f, 0.f};
    #pragma unroll 8
    for (int ll = 0; ll < 32; ++ll) {
        vf4 v = *(const vf4*)(base + (size_t)ll * D);
        s.x += v.x; s.y += v.y; s.z += v.z; s.w += v.w;
    }
    *(vf4*)(partial + ((size_t)(b * 32 + chunk)) * 512 + d4) = s;

    // elect last block of this batch
    __threadfence();                 // release partial write (device scope)
    __shared__ int winner;
    if (j == 0) winner = (atomicAdd(&counters[b], 1) == 31);
    __syncthreads();
    if (!winner) return;
    __threadfence();                 // acquire other blocks' partials

    // ---- head MLP for batch b (128 threads) ----
    __shared__ float fm[D];
    __shared__ float red[DH];
    for (int d = j; d < D; d += DH) {
        float acc = 0.f;
        const float* p = partial + (size_t)b * 32 * 512 + d;
        for (int c = 0; c < 32; ++c) acc += p[c * 512];
        fm[d] = acc * (1.0f / (float)L);
    }
    __syncthreads();
    float h = b1[j];
    const vf4* fm4 = (const vf4*)fm;
    #pragma unroll 8
    for (int q = 0; q < D / 4; ++q) {
        vf4 f = fm4[q];
        h = fmaf(f.x, W1[(4 * q + 0) * DH + j], h);
        h = fmaf(f.y, W1[(4 * q + 1) * DH + j], h);
        h = fmaf(f.z, W1[(4 * q + 2) * DH + j], h);
        h = fmaf(f.w, W1[(4 * q + 3) * DH + j], h);
    }

    red[j] = h; __syncthreads();
    for (int st = 64; st > 0; st >>= 1) { if (j < st) red[j] += red[j + st]; __syncthreads(); }
    float mu = red[0] * (1.f / (float)DH);
    __syncthreads();
    float hc = h - mu;
    red[j] = hc * hc; __syncthreads();
    for (int st = 64; st > 0; st >>= 1) { if (j < st) red[j] += red[j + st]; __syncthreads(); }
    float var = red[0] * (1.f / (float)DH);
    __syncthreads();

    float hn = hc * rsqrtf(var + 1e-5f) * ln_g[j] + ln_b[j];
    hn = fmaxf(hn, 0.f);

    red[j] = hn * W2[j * 2 + 0]; __syncthreads();
    for (int st = 64; st > 0; st >>= 1) { if (j < st) red[j] += red[j + st]; __syncthreads(); }
    float p0 = red[0];
    __syncthreads();
    red[j] = hn * W2[j * 2 + 1]; __syncthreads();
    for (int st = 64; st > 0; st >>= 1) { if (j < st) red[j] += red[j + st]; __syncthreads(); }
    float p1 = red[0];

    if (j == 0) {
        float a  = 0.00015f / (1.f + expf(-(p0 + b2[0])));
        float be = 0.00015f / (1.f + expf(-(p1 + b2[1])));
        ab[b] = a; ab[8 + b] = be;
        out_tail[b] = a; out_tail[8 + b] = be;
    }
}

// ---------------- kernel B: MEGA — vblur + hblur + synth, no hmask ws -------
// grid: B * 64 strips * 2 half-widths = 1024 blocks, 256 threads.
// vblur FIRST: thread t keeps a 21-row register window over RAW mask for its
// col pair (x0+2t); threads 0..4 keep a second window for the 10 interior
// halo cols. Per row: vblur -> LDS (double-buffered, 1 barrier) -> hblur from
// LDS -> elementwise synth. Outer-image halo = compile-time zero LDS slots.
__global__ __launch_bounds__(256) void mega_kernel(
        const float* __restrict__ x_bg, const float* __restrict__ noise,
        const float* __restrict__ mask, const float* __restrict__ ab,
        float* __restrict__ out, BlurW kw) {
    int blk = blockIdx.x;            // 0..1023
    int b   = blk >> 7;
    int rem = blk & 127;
    int s   = rem >> 1;              // strip 0..63
    int wj  = rem & 1;
    int h0  = s * TH;
    int t   = threadIdx.x;           // 0..255
    int x0  = wj * 512;
    bool left = (wj == 0);

    __shared__ float vrow[2][536];   // vblurred cols cbase..cbase+531; cbase=x0-10
    const vf2 zero2 = {0.f, 0.f};

    // permanent zero slots (outside-image halo)
    if (t < 10) {
        int zi = left ? t : (522 + t);
        vrow[0][zi] = 0.f;
        vrow[1][zi] = 0.f;
    }

    // main window: cols x0+2t, x0+2t+1
    const float* mcol = mask + (size_t)b * NPIX + x0 + 2 * t;
    vf2 mwin[21];
    #pragma unroll
    for (int k = 0; k < 21; ++k) {
        int hy = h0 - 10 + k;
        mwin[k] = (hy >= 0) ? *(const vf2*)(mcol + (size_t)hy * W) : zero2;
    }

    // halo window: threads 0..4 own interior halo col pairs
    int hcol_off = left ? (512 + 2 * t) : (502 + 2 * t - 512);  // relative to x0
    const float* hcol = mask + (size_t)b * NPIX + x0 + hcol_off;
    int hs_i = left ? (522 + 2 * t) : (2 * t);                  // LDS slot
    vf2 hwin[21];
    if (t < 5) {
        #pragma unroll
        for (int k = 0; k < 21; ++k) {
            int hy = h0 - 10 + k;
            hwin[k] = (hy >= 0) ? *(const vf2*)(hcol + (size_t)hy * W) : zero2;
        }
    }

    float alpha = ab[b], beta = ab[8 + b];
    int p = 0;

    for (int r = 0; r < TH; ++r) {
        int h = h0 + r;

        // vblur from register windows (symmetric kernel)
        vf2 vm;
        {
            float ax = 0.f, ay = 0.f;
            #pragma unroll
            for (int k = 0; k < 10; ++k) {
                ax = fmaf(kw.w[k], mwin[k].x + mwin[20 - k].x, ax);
                ay = fmaf(kw.w[k], mwin[k].y + mwin[20 - k].y, ay);
            }
            vm.x = fmaf(kw.w[10], mwin[10].x, ax);
            vm.y = fmaf(kw.w[10], mwin[10].y, ay);
        }
        *(vf2*)&vrow[p][10 + 2 * t] = vm;
        if (t < 5) {
            float ax = 0.f, ay = 0.f;
            #pragma unroll
            for (int k = 0; k < 10; ++k) {
                ax = fmaf(kw.w[k], hwin[k].x + hwin[20 - k].x, ax);
                ay = fmaf(kw.w[k], hwin[k].y + hwin[20 - k].y, ay);
            }
            vf2 vh;
            vh.x = fmaf(kw.w[10], hwin[10].x, ax);
            vh.y = fmaf(kw.w[10], hwin[10].y, ay);
            *(vf2*)&vrow[p][hs_i] = vh;
        }
        __syncthreads();

        // hblur from LDS: output cols x0+2t, x0+2t+1 need vrow[2t .. 2t+21]
        vf2 vv[11];
        #pragma unroll
        for (int q = 0; q < 11; ++q) vv[q] = *(const vf2*)&vrow[p][2 * t + 2 * q];
        float omx = 0.f, omy = 0.f;
        #pragma unroll
        for (int q = 0; q < 10; ++q) {
            float fj  = vv[q >> 1][q & 1];
            float f20 = vv[(20 - q) >> 1][(20 - q) & 1];
            float fj1 = vv[(q + 1) >> 1][(q + 1) & 1];
            float f21 = vv[(21 - q) >> 1][(21 - q) & 1];
            omx = fmaf(kw.w[q], fj + f20, omx);
            omy = fmaf(kw.w[q], fj1 + f21, omy);
        }
        omx = fmaf(kw.w[10], vv[5].x, omx);
        omy = fmaf(kw.w[10], vv[5].y, omy);

        // elementwise synth, 3 channels
        #pragma unroll
        for (int c = 0; c < C; ++c) {
            size_t idx = (((size_t)(b * C + c) * H) + h) * W + x0 + 2 * t;
            vf2 x  = *(const vf2*)(x_bg + idx);
            vf2 nz = *(const vf2*)(noise + idx);
            vf2 o;
            float sgx = sqrtf(fmaxf(fmaf(alpha, x.x, beta), 1e-7f));
            float sgy = sqrtf(fmaxf(fmaf(alpha, x.y, beta), 1e-7f));
            o.x = fmaf(1.5f * nz.x * sgx, omx, x.x);
            o.y = fmaf(1.5f * nz.y * sgy, omy, x.y);
            __builtin_nontemporal_store(o, (vf2*)(out + idx));
        }

        // advance windows
        if (r < TH - 1) {
            int hy = h0 + r + 11;    // always >= 11
            #pragma unroll
            for (int i = 0; i < 20; ++i) mwin[i] = mwin[i + 1];
            mwin[20] = (hy < H) ? *(const vf2*)(mcol + (size_t)hy * W) : zero2;
            if (t < 5) {
                #pragma unroll
                for (int i = 0; i < 20; ++i) hwin[i] = hwin[i + 1];
                hwin[20] = (hy < H) ? *(const vf2*)(hcol + (size_t)hy * W) : zero2;
            }
            p ^= 1;
        }
    }
}

extern "C" void kernel_launch(void* const* d_in, const int* in_sizes, int n_in,
                              void* d_out, int out_size, void* d_ws, size_t ws_size,
                              hipStream_t stream) {
    const float* x_bg = (const float*)d_in[0];
    const float* feat = (const float*)d_in[1];
    const float* mask = (const float*)d_in[2];
    const float* noise = (const float*)d_in[3];
    const float* W1 = (const float*)d_in[4];
    const float* b1 = (const float*)d_in[5];
    const float* ln_g = (const float*)d_in[6];
    const float* ln_b = (const float*)d_in[7];
    const float* W2 = (const float*)d_in[8];
    const float* b2 = (const float*)d_in[9];
    float* out = (float*)d_out;

    // ws layout (floats): [0, 131072) partial colsums (8*32*512)
    //                     [131072, +16) ab | [131072+32, +8 ints) counters
    float* ws_f = (float*)d_ws;
    float* partial = ws_f;
    float* ab = ws_f + 131072;
    int* counters = (int*)(ws_f + 131072 + 32);

    BlurW kw;
    {
        double g[21], ssum = 0.0;
        for (int i = 0; i < 21; ++i) { double x = (double)(i - 10); g[i] = exp(-x * x / 50.0); ssum += g[i]; }
        for (int i = 0; i < 21; ++i) kw.w[i] = (float)(g[i] / ssum);
    }

    hipMemsetAsync(counters, 0, 8 * sizeof(int), stream);
    colsum_head_kernel<<<256, 128, 0, stream>>>(feat, partial, counters,
                                                W1, b1, ln_g, ln_b, W2, b2,
                                                ab, out + NOISY_ELEMS);
    mega_kernel<<<1024, 256, 0, stream>>>(x_bg, noise, mask, ab, out, kw);
}